// Round 4
// baseline (1078.692 us; speedup 1.0000x reference)
//
#include <hip/hip_runtime.h>
#include <math.h>

#define B_TOTAL 2048
#define T_LEN   512
#define IN_D    6
#define HID     64
#define LAT     16
#define GR      8          // rows per group
#define RT      16         // rows per block (two pipelined groups P,Q)
#define THREADS 256        // 4 waves; wave w owns output units j in [16w,16w+16) for all 3 gates
#define ASTRIDE 104        // A row stride in bf16 elems (208B = 13x16B, breaks bank aliasing)

typedef __attribute__((ext_vector_type(8))) short bfrag;   // 8 bf16 = 4 VGPRs
typedef __attribute__((ext_vector_type(4))) float ffrag;   // 4 fp32 acc

__device__ __forceinline__ float fast_sigmoid(float x){
    float e = __expf(-x);
    return __fdividef(1.0f, 1.0f + e);
}
__device__ __forceinline__ float fast_tanh(float x){
    float e = __expf(2.0f * x);
    return 1.0f - __fdividef(2.0f, e + 1.0f);
}
__device__ __forceinline__ unsigned short f2bf_rne(float f){
    unsigned u = __float_as_uint(f);
    return (unsigned short)((u + 0x7fffu + ((u >> 16) & 1u)) >> 16);
}
__device__ __forceinline__ float bf2f(unsigned short b){
    return __uint_as_float(((unsigned)b) << 16);
}

// packed hi/lo bf16 write of one x element into A-tile column 64+xd
__device__ __forceinline__ void write_x_slot(unsigned short (*Ab)[16][ASTRIDE],
                                             int xm, int xd, float v){
    unsigned short hi16 = f2bf_rne(v);
    float res = v - bf2f(hi16);
    Ab[0][xm][64 + xd] = hi16;
    Ab[1][xm][64 + xd] = (unsigned short)(__float_as_uint(res) >> 16);
}

extern "C" __global__ void
__attribute__((amdgpu_flat_work_group_size(THREADS, THREADS), amdgpu_waves_per_eu(1, 1)))
glsde_kernel(const float* __restrict__ x,
             const float* __restrict__ eWih, const float* __restrict__ eWhh,
             const float* __restrict__ ebih, const float* __restrict__ ebhh,
             const float* __restrict__ muW,  const float* __restrict__ mub,
             const float* __restrict__ lvW,  const float* __restrict__ lvb,
             const float* __restrict__ oW,   const float* __restrict__ ob,
             const float* __restrict__ dfW,  const float* __restrict__ dfb,
             const float* __restrict__ dWih, const float* __restrict__ dWhh,
             const float* __restrict__ dbih, const float* __restrict__ dbhh,
             float* __restrict__ out)
{
    __shared__ __align__(16) unsigned short A_P[2][16][ASTRIDE];  // [plane hi/lo][m][k]
    __shared__ __align__(16) unsigned short A_Q[2][16][ASTRIDE];
    __shared__ float hfp[RT][HID];
    __shared__ float zsh[RT][LAT];
    __shared__ float zdsh[RT][HID];
    __shared__ float xgdsh[RT][3];
    __shared__ float outsh[RT][T_LEN];

    const int tid  = threadIdx.x;
    const int wave = tid >> 6;
    const int lane = tid & 63;
    const int nloc = lane & 15;
    const int quad = lane >> 4;
    const int mA   = lane & 15;
    const int j    = wave * 16 + nloc;   // output unit 0..63
    const int b0   = blockIdx.x * RT;

    const float S1 = 1.44269504088896340736f;  // log2(e): sigmoid via exp2
    const float S2 = 2.0f * S1;                // tanh via exp2 of 2x

    // ---- weights (pre-scaled) -> registers, hi/lo bf16 split, loaded ONCE ----
    bfrag BrH[3], BrL[3], BzH[3], BzL[3], BnhH[2], BnhL[2], BnxH, BnxL;
    {
        const float* wr  = eWhh + (size_t)(      j) * HID;
        const float* wz  = eWhh + (size_t)( 64 + j) * HID;
        const float* wn  = eWhh + (size_t)(128 + j) * HID;
        #pragma unroll
        for (int kt = 0; kt < 2; ++kt){
            const int o = kt * 32 + quad * 8;
            #pragma unroll
            for (int e = 0; e < 8; ++e){
                float a = wr[o+e] * S1, b = wz[o+e] * S1, c = wn[o+e] * S2;
                unsigned short ah = f2bf_rne(a), bh = f2bf_rne(b), ch = f2bf_rne(c);
                BrH[kt][e]  = (short)ah; BrL[kt][e]  = (short)f2bf_rne(a - bf2f(ah));
                BzH[kt][e]  = (short)bh; BzL[kt][e]  = (short)f2bf_rne(b - bf2f(bh));
                BnhH[kt][e] = (short)ch; BnhL[kt][e] = (short)f2bf_rne(c - bf2f(ch));
            }
        }
        const float* ir  = eWih + (size_t)(      j) * IN_D;
        const float* iz  = eWih + (size_t)( 64 + j) * IN_D;
        const float* inn = eWih + (size_t)(128 + j) * IN_D;
        #pragma unroll
        for (int e = 0; e < 8; ++e){
            float a = (quad == 0 && e < IN_D) ? ir[e]  * S1 : 0.0f;
            float b = (quad == 0 && e < IN_D) ? iz[e]  * S1 : 0.0f;
            float c = (quad == 0 && e < IN_D) ? inn[e] * S2 : 0.0f;
            unsigned short ah = f2bf_rne(a), bh = f2bf_rne(b), ch = f2bf_rne(c);
            BrH[2][e] = (short)ah; BrL[2][e] = (short)f2bf_rne(a - bf2f(ah));
            BzH[2][e] = (short)bh; BzL[2][e] = (short)f2bf_rne(b - bf2f(bh));
            BnxH[e]   = (short)ch; BnxL[e]   = (short)f2bf_rne(c - bf2f(ch));
        }
    }
    const float bias_r = (ebih[j]      + ebhh[j])      * S1;
    const float bias_z = (ebih[64 + j] + ebhh[64 + j]) * S1;
    const float bihn2  = ebih[128 + j] * S2;
    const float bhhn2  = ebhh[128 + j] * S2;

    // ---- zero A buffers (pad rows/cols stay 0 forever) ----
    {
        unsigned* ap = (unsigned*)A_P;
        for (int i = tid; i < (int)(sizeof(A_P) / 4); i += THREADS) ap[i] = 0u;
        unsigned* aq = (unsigned*)A_Q;
        for (int i = tid; i < (int)(sizeof(A_Q) / 4); i += THREADS) aq[i] = 0u;
    }
    __syncthreads();

    // ---- x loader lanes: wave0 lanes feed P, wave1 lanes feed Q ----
    const bool isPx = (tid < GR * IN_D);
    const int  qq   = tid - 64;
    const bool isQx = (qq >= 0) && (qq < GR * IN_D);
    const int xmP = isPx ? (tid / IN_D) : 0, xdP = isPx ? (tid % IN_D) : 0;
    const int xmQ = isQx ? (qq  / IN_D) : 0, xdQ = isQx ? (qq  % IN_D) : 0;
    const float* pxP = x + (size_t)(b0 + xmP)      * T_LEN * IN_D + xdP;
    const float* pxQ = x + (size_t)(b0 + GR + xmQ) * T_LEN * IN_D + xdQ;

    if (isPx) write_x_slot(A_P, xmP, xdP, pxP[0]);
    if (isQx) write_x_slot(A_Q, xmQ, xdQ, pxQ[0]);
    float xvP = isPx ? pxP[1 * IN_D] : 0.f;   // x_P(1)
    float xvQ = 0.f;                          // set at end of peel
    __syncthreads();

    float hregP[4] = {0,0,0,0}, hregQ[4] = {0,0,0,0};
    ffrag accPr, accPz, accPnh, accPnx;
    ffrag accQr, accQz, accQnh, accQnx;
    bfrag Ah[3], Al[3];
    float hn[4];
    const ffrag FZ = {0.f, 0.f, 0.f, 0.f};

#define READ_FR(Ab) \
    do { \
        const unsigned short* ah_ = &Ab[0][mA][0]; \
        const unsigned short* al_ = &Ab[1][mA][0]; \
        _Pragma("unroll") \
        for (int kt = 0; kt < 3; ++kt){ \
            Ah[kt] = *(const bfrag*)(ah_ + kt * 32 + quad * 8); \
            Al[kt] = *(const bfrag*)(al_ + kt * 32 + quad * 8); \
        } \
    } while (0)

#define MFMA27(aR, aZ, aNH, aNX) \
    do { \
        aR = FZ; aZ = FZ; aNH = FZ; aNX = FZ; \
        _Pragma("unroll") \
        for (int kt = 0; kt < 2; ++kt){ \
            aR  = __builtin_amdgcn_mfma_f32_16x16x32_bf16(Ah[kt], BrH[kt],  aR,  0,0,0); \
            aZ  = __builtin_amdgcn_mfma_f32_16x16x32_bf16(Ah[kt], BzH[kt],  aZ,  0,0,0); \
            aNH = __builtin_amdgcn_mfma_f32_16x16x32_bf16(Ah[kt], BnhH[kt], aNH, 0,0,0); \
            aR  = __builtin_amdgcn_mfma_f32_16x16x32_bf16(Ah[kt], BrL[kt],  aR,  0,0,0); \
            aZ  = __builtin_amdgcn_mfma_f32_16x16x32_bf16(Ah[kt], BzL[kt],  aZ,  0,0,0); \
            aNH = __builtin_amdgcn_mfma_f32_16x16x32_bf16(Ah[kt], BnhL[kt], aNH, 0,0,0); \
            aR  = __builtin_amdgcn_mfma_f32_16x16x32_bf16(Al[kt], BrH[kt],  aR,  0,0,0); \
            aZ  = __builtin_amdgcn_mfma_f32_16x16x32_bf16(Al[kt], BzH[kt],  aZ,  0,0,0); \
            aNH = __builtin_amdgcn_mfma_f32_16x16x32_bf16(Al[kt], BnhH[kt], aNH, 0,0,0); \
        } \
        aR  = __builtin_amdgcn_mfma_f32_16x16x32_bf16(Ah[2], BrH[2], aR,  0,0,0); \
        aZ  = __builtin_amdgcn_mfma_f32_16x16x32_bf16(Ah[2], BzH[2], aZ,  0,0,0); \
        aNX = __builtin_amdgcn_mfma_f32_16x16x32_bf16(Ah[2], BnxH,   aNX, 0,0,0); \
        aR  = __builtin_amdgcn_mfma_f32_16x16x32_bf16(Ah[2], BrL[2], aR,  0,0,0); \
        aZ  = __builtin_amdgcn_mfma_f32_16x16x32_bf16(Ah[2], BzL[2], aZ,  0,0,0); \
        aNX = __builtin_amdgcn_mfma_f32_16x16x32_bf16(Ah[2], BnxL,   aNX, 0,0,0); \
        aR  = __builtin_amdgcn_mfma_f32_16x16x32_bf16(Al[2], BrH[2], aR,  0,0,0); \
        aZ  = __builtin_amdgcn_mfma_f32_16x16x32_bf16(Al[2], BzH[2], aZ,  0,0,0); \
        aNX = __builtin_amdgcn_mfma_f32_16x16x32_bf16(Al[2], BnxH,   aNX, 0,0,0); \
    } while (0)

    // sigmoid(a)=rcp(1+exp2(-a')), tanh(v)=1-2*rcp(exp2(y')+1); scales folded into weights
#define GRU_FIN(aR, aZ, aNH, aNX, hreg) \
    do { \
        _Pragma("unroll") \
        for (int r = 0; r < 4; ++r){ \
            float rg = __fdividef(1.0f, 1.0f + exp2f(-(aR[r] + bias_r))); \
            float zg = __fdividef(1.0f, 1.0f + exp2f(-(aZ[r] + bias_z))); \
            float yy = aNX[r] + bihn2 + rg * (aNH[r] + bhhn2); \
            float ng = 1.0f - __fdividef(2.0f, exp2f(yy) + 1.0f); \
            hn[r] = (1.0f - zg) * ng + zg * hreg[r]; \
            hreg[r] = hn[r]; \
        } \
    } while (0)

#define WRITE_H(Ab) \
    do { if (lane < 32){ \
        _Pragma("unroll") \
        for (int r = 0; r < 4; ++r){ \
            unsigned short hi16 = f2bf_rne(hn[r]); \
            float res = hn[r] - bf2f(hi16); \
            Ab[0][quad * 4 + r][j] = hi16; \
            Ab[1][quad * 4 + r][j] = (unsigned short)(__float_as_uint(res) >> 16); \
        } } \
    } while (0)

    // ================= encoder GRU: 512 steps, 2 groups pipelined =================
    { // peeled t = 0 (no fin_Q yet)
        float xnQ = isQx ? pxQ[1 * IN_D] : 0.f;   // x_Q(1)
        float xnP = isPx ? pxP[2 * IN_D] : 0.f;   // x_P(2)
        READ_FR(A_P);
        MFMA27(accPr, accPz, accPnh, accPnx);
        __syncthreads();
        READ_FR(A_Q);
        MFMA27(accQr, accQz, accQnh, accQnx);
        GRU_FIN(accPr, accPz, accPnh, accPnx, hregP);   // overlaps MFMA_Q pipe
        WRITE_H(A_P);
        if (isPx) write_x_slot(A_P, xmP, xdP, xvP);
        xvP = xnP; xvQ = xnQ;
        __syncthreads();
    }
    for (int t = 1; t < T_LEN; ++t){
        const int tn1 = (t + 1 < T_LEN) ? (t + 1) : (T_LEN - 1);
        const int tn2 = (t + 2 < T_LEN) ? (t + 2) : (T_LEN - 1);
        float xnQ = isQx ? pxQ[(size_t)tn1 * IN_D] : 0.f;
        float xnP = isPx ? pxP[(size_t)tn2 * IN_D] : 0.f;
        // region 1: MFMA_P(t) || fin_Q(t-1)
        READ_FR(A_P);
        MFMA27(accPr, accPz, accPnh, accPnx);
        GRU_FIN(accQr, accQz, accQnh, accQnx, hregQ);
        WRITE_H(A_Q);
        if (isQx) write_x_slot(A_Q, xmQ, xdQ, xvQ);
        __syncthreads();
        // region 2: MFMA_Q(t) || fin_P(t)
        READ_FR(A_Q);
        MFMA27(accQr, accQz, accQnh, accQnx);
        GRU_FIN(accPr, accPz, accPnh, accPnx, hregP);
        WRITE_H(A_P);
        if (isPx) write_x_slot(A_P, xmP, xdP, xvP);
        xvQ = xnQ; xvP = xnP;
        __syncthreads();
    }
    GRU_FIN(accQr, accQz, accQnh, accQnx, hregQ);   // h_Q(512)

    // ---- publish final h (fp32, from registers) ----
    if (lane < 32){
        #pragma unroll
        for (int r = 0; r < 4; ++r){
            hfp[quad * 4 + r][j]      = hregP[r];
            hfp[GR + quad * 4 + r][j] = hregQ[r];
        }
    }
    __syncthreads();

    // ================= heads: mu, logvar, z0 (256 threads = 16 rows x 16 lat) ====
    const int zrow = tid >> 4, zi = tid & 15;
    float z0v = 0.0f;
    {
        float am = mub[zi], al = lvb[zi];
        const float4* pm = (const float4*)(muW + (size_t)zi * HID);
        const float4* pq = (const float4*)(lvW + (size_t)zi * HID);
        const float4* ph = (const float4*)(&hfp[zrow][0]);
        #pragma unroll
        for (int q = 0; q < 16; ++q){
            float4 wm = pm[q], wl = pq[q], hv = ph[q];
            am += wm.x*hv.x + wm.y*hv.y + wm.z*hv.z + wm.w*hv.w;
            al += wl.x*hv.x + wl.y*hv.y + wl.z*hv.z + wl.w*hv.w;
        }
        const size_t muBase = (size_t)B_TOTAL * T_LEN;
        out[muBase + (size_t)(b0 + zrow) * LAT + zi] = am;
        out[muBase + (size_t)B_TOTAL * LAT + (size_t)(b0 + zrow) * LAT + zi] = al;
        z0v = am + __expf(0.5f * al);
    }

    // ================= ODE: RK4, 24 fixed steps on [0,1] =================
    {
        float ows[16];
        {
            const float4* pw = (const float4*)(oW + (size_t)zi * LAT);
            #pragma unroll
            for (int q = 0; q < 4; ++q){
                float4 w = pw[q];
                ows[4*q+0] = w.x; ows[4*q+1] = w.y; ows[4*q+2] = w.z; ows[4*q+3] = w.w;
            }
        }
        const float obv = ob[zi];
        float z = z0v;
        const float hstep = 1.0f / 24.0f;
        for (int s = 0; s < 24; ++s){
            float y, k1, k2, k3, k4;
            y = z;
            { float acc = obv;
              #pragma unroll
              for (int jj = 0; jj < 16; ++jj){ float yj = __shfl(y, jj, 16); acc = fmaf(ows[jj], yj, acc); }
              k1 = fmaxf(acc, 0.0f); }
            y = z + 0.5f * hstep * k1;
            { float acc = obv;
              #pragma unroll
              for (int jj = 0; jj < 16; ++jj){ float yj = __shfl(y, jj, 16); acc = fmaf(ows[jj], yj, acc); }
              k2 = fmaxf(acc, 0.0f); }
            y = z + 0.5f * hstep * k2;
            { float acc = obv;
              #pragma unroll
              for (int jj = 0; jj < 16; ++jj){ float yj = __shfl(y, jj, 16); acc = fmaf(ows[jj], yj, acc); }
              k3 = fmaxf(acc, 0.0f); }
            y = z + hstep * k3;
            { float acc = obv;
              #pragma unroll
              for (int jj = 0; jj < 16; ++jj){ float yj = __shfl(y, jj, 16); acc = fmaf(ows[jj], yj, acc); }
              k4 = fmaxf(acc, 0.0f); }
            z += (hstep / 6.0f) * (k1 + 2.0f*k2 + 2.0f*k3 + k4);
        }
        zsh[zrow][zi] = z;
    }
    __syncthreads();

    // ================= decoder fc: zd = relu(z @ dfW.T + dfb) =================
    for (int idx = tid; idx < RT * HID; idx += THREADS){
        const int row = idx >> 6, o = idx & 63;
        float acc = dfb[o];
        const float4* pw = (const float4*)(dfW + (size_t)o * LAT);
        const float4* pz = (const float4*)(&zsh[row][0]);
        #pragma unroll
        for (int q = 0; q < 4; ++q){
            float4 w = pw[q], zv = pz[q];
            acc += w.x*zv.x + w.y*zv.y + w.z*zv.z + w.w*zv.w;
        }
        zdsh[row][o] = fmaxf(acc, 0.0f);
    }
    __syncthreads();

    // xg_dec = zd @ dec_Wih.T + dec_bih
    if (tid < RT * 3){
        const int row = tid / 3, gg = tid % 3;
        float acc = dbih[gg];
        const float4* pw = (const float4*)(dWih + (size_t)gg * HID);
        const float4* pz = (const float4*)(&zdsh[row][0]);
        #pragma unroll
        for (int q = 0; q < 16; ++q){
            float4 w = pw[q], zv = pz[q];
            acc += w.x*zv.x + w.y*zv.y + w.z*zv.z + w.w*zv.w;
        }
        xgdsh[row][gg] = acc;
    }
    __syncthreads();

    // ================= decoder GRU (hidden dim 1), 512 steps =================
    if (tid < RT){
        const int row = tid;
        const float xr = xgdsh[row][0], xz = xgdsh[row][1], xn = xgdsh[row][2];
        const float A0 = dWhh[0], A1 = dWhh[1], A2 = dWhh[2];
        const float c0 = dbhh[0], c1 = dbhh[1], c2 = dbhh[2];
        float h = 0.0f;
        for (int t = 0; t < T_LEN; ++t){
            float rr = fast_sigmoid(xr + A0 * h + c0);
            float zz = fast_sigmoid(xz + A1 * h + c1);
            float nn = fast_tanh(xn + rr * (A2 * h + c2));
            h = (1.0f - zz) * nn + zz * h;
            outsh[row][t] = h;
        }
    }
    __syncthreads();

    // coalesced x_recon write: rows b0..b0+15 contiguous
    {
        const float4* ps = (const float4*)(&outsh[0][0]);
        float4* pd = (float4*)out;
        const size_t base4 = ((size_t)b0 * T_LEN) >> 2;
        for (int q = tid; q < (RT * T_LEN) / 4; q += THREADS)
            pd[base4 + q] = ps[q];
    }
}

extern "C" void kernel_launch(void* const* d_in, const int* in_sizes, int n_in,
                              void* d_out, int out_size, void* d_ws, size_t ws_size,
                              hipStream_t stream){
    glsde_kernel<<<B_TOTAL / RT, THREADS, 0, stream>>>(
        (const float*)d_in[0],  (const float*)d_in[1],  (const float*)d_in[2],
        (const float*)d_in[3],  (const float*)d_in[4],  (const float*)d_in[5],
        (const float*)d_in[6],  (const float*)d_in[7],  (const float*)d_in[8],
        (const float*)d_in[9],  (const float*)d_in[10], (const float*)d_in[11],
        (const float*)d_in[12], (const float*)d_in[13], (const float*)d_in[14],
        (const float*)d_in[15], (const float*)d_in[16], (float*)d_out);
}

// Round 5
// 432.495 us; speedup vs baseline: 2.4941x; 2.4941x over previous
//
#include <hip/hip_runtime.h>
#include <math.h>

#define B_TOTAL 2048
#define T_LEN   512
#define IN_D    6
#define HID     64
#define LAT     16
#define ROWS    8          // batch rows per block, mapped to M-tile rows {0,1,4,5,8,9,12,13}
#define THREADS 256        // 4 waves; wave w owns output units j in [16w,16w+16) for all 3 gates
#define ASTRIDE 104        // A row stride in bf16 elems (208B = 13x16B aligned)

typedef __attribute__((ext_vector_type(8))) short bfrag;   // 8 bf16 = 4 VGPRs
typedef __attribute__((ext_vector_type(4))) float ffrag;   // 4 fp32 acc

__device__ __forceinline__ float fast_sigmoid(float x){
    float e = __expf(-x);
    return __fdividef(1.0f, 1.0f + e);
}
__device__ __forceinline__ float fast_tanh(float x){
    float e = __expf(2.0f * x);
    return 1.0f - __fdividef(2.0f, e + 1.0f);
}
__device__ __forceinline__ unsigned short f2bf_rne(float f){
    unsigned u = __float_as_uint(f);
    return (unsigned short)((u + 0x7fffu + ((u >> 16) & 1u)) >> 16);
}

// batch row b (0..7) -> M-tile row: rows {0,1,4,5,8,9,12,13}; every lane quad
// gets 2 valid D rows (reg 0,1) -> finalize is 2 regs on ALL lanes.
__device__ __forceinline__ int mrow_of(int b){ return ((b >> 1) << 2) + (b & 1); }

extern "C" __global__ void
__attribute__((amdgpu_flat_work_group_size(THREADS, THREADS), amdgpu_waves_per_eu(1, 1)))
glsde_kernel(const float* __restrict__ x,
             const float* __restrict__ eWih, const float* __restrict__ eWhh,
             const float* __restrict__ ebih, const float* __restrict__ ebhh,
             const float* __restrict__ muW,  const float* __restrict__ mub,
             const float* __restrict__ lvW,  const float* __restrict__ lvb,
             const float* __restrict__ oW,   const float* __restrict__ ob,
             const float* __restrict__ dfW,  const float* __restrict__ dfb,
             const float* __restrict__ dWih, const float* __restrict__ dWhh,
             const float* __restrict__ dbih, const float* __restrict__ dbhh,
             float* __restrict__ out)
{
    __shared__ __align__(16) unsigned short Abuf[2][16][ASTRIDE];  // [buf][m][k] bf16
    __shared__ float hfp[ROWS][HID];
    __shared__ float zsh[ROWS][LAT];
    __shared__ float zdsh[ROWS][HID];
    __shared__ float xgdsh[ROWS][3];
    __shared__ float outsh[ROWS][T_LEN];

    const int tid  = threadIdx.x;
    const int wave = tid >> 6;
    const int lane = tid & 63;
    const int nloc = lane & 15;
    const int quad = lane >> 4;
    const int mA   = lane & 15;
    const int j    = wave * 16 + nloc;   // output unit 0..63
    const int b0   = blockIdx.x * ROWS;

    const float S1 = 1.44269504088896340736f;  // log2(e): sigmoid via exp2
    const float S2 = 2.0f * S1;                // tanh via exp2(2x)

    // ---- weights (pre-scaled by S1/S2) -> registers, plain bf16, loaded ONCE ----
    // B[k][n=j]: lane holds k = kt*32 + quad*8 + e. kt 0,1 = h-part (Whh),
    // kt 2 = x-part (Wih, k=64..69 valid on quad 0 only).
    bfrag Br[3], Bz[3], Bnh[2], Bnx;
    {
        const float* wr  = eWhh + (size_t)(      j) * HID;
        const float* wz  = eWhh + (size_t)( 64 + j) * HID;
        const float* wn  = eWhh + (size_t)(128 + j) * HID;
        #pragma unroll
        for (int kt = 0; kt < 2; ++kt){
            const int o = kt * 32 + quad * 8;
            #pragma unroll
            for (int e = 0; e < 8; ++e){
                Br[kt][e]  = (short)f2bf_rne(wr[o+e] * S1);
                Bz[kt][e]  = (short)f2bf_rne(wz[o+e] * S1);
                Bnh[kt][e] = (short)f2bf_rne(wn[o+e] * S2);
            }
        }
        const float* ir  = eWih + (size_t)(      j) * IN_D;
        const float* iz  = eWih + (size_t)( 64 + j) * IN_D;
        const float* inn = eWih + (size_t)(128 + j) * IN_D;
        #pragma unroll
        for (int e = 0; e < 8; ++e){
            bool v = (quad == 0 && e < IN_D);
            Br[2][e] = v ? (short)f2bf_rne(ir[e]  * S1) : (short)0;
            Bz[2][e] = v ? (short)f2bf_rne(iz[e]  * S1) : (short)0;
            Bnx[e]   = v ? (short)f2bf_rne(inn[e] * S2) : (short)0;
        }
    }
    const float bias_r = (ebih[j]      + ebhh[j])      * S1;
    const float bias_z = (ebih[64 + j] + ebhh[64 + j]) * S1;
    const float bihn2  = ebih[128 + j] * S2;
    const float bhhn2  = ebhh[128 + j] * S2;

    // ---- zero A buffers (unused rows/cols stay 0 forever) ----
    {
        unsigned* ap = (unsigned*)Abuf;
        for (int i = tid; i < (int)(sizeof(Abuf) / 4); i += THREADS) ap[i] = 0u;
    }
    __syncthreads();

    // ---- x loader lanes: tid < 48 ----
    const bool isx = (tid < ROWS * IN_D);
    const int xb = isx ? (tid / IN_D) : 0;        // batch row 0..7
    const int xd = isx ? (tid % IN_D) : 0;
    const int xm = mrow_of(xb);                   // M-tile row
    const float* xp = x + (size_t)(b0 + xb) * T_LEN * IN_D + xd;
    if (isx) Abuf[0][xm][64 + xd] = f2bf_rne(xp[0]);
    __syncthreads();

    // lane (quad, j) owns batch rows 2*quad, 2*quad+1 (M rows quad*4, quad*4+1)
    float hreg[2] = {0.f, 0.f};
    const ffrag FZ = {0.f, 0.f, 0.f, 0.f};

    // ================= encoder GRU: 512 steps, 1 barrier/step =================
    int cb = 0;
    for (int t = 0; t < T_LEN; ++t){
        float xv = 0.0f;
        if (isx){
            int tn = (t + 1 < T_LEN) ? (t + 1) : (T_LEN - 1);
            xv = xp[(size_t)tn * IN_D];
        }

        // A fragments: lane reads row mA, k = kt*32 + quad*8 .. +8
        bfrag Ah[3];
        {
            const unsigned short* ah = &Abuf[cb][mA][0];
            #pragma unroll
            for (int kt = 0; kt < 3; ++kt)
                Ah[kt] = *(const bfrag*)(ah + kt * 32 + quad * 8);
        }

        ffrag aR = FZ, aZ = FZ, aNH = FZ, aNX = FZ;
        aR  = __builtin_amdgcn_mfma_f32_16x16x32_bf16(Ah[0], Br[0],  aR,  0,0,0);
        aZ  = __builtin_amdgcn_mfma_f32_16x16x32_bf16(Ah[0], Bz[0],  aZ,  0,0,0);
        aNH = __builtin_amdgcn_mfma_f32_16x16x32_bf16(Ah[0], Bnh[0], aNH, 0,0,0);
        aR  = __builtin_amdgcn_mfma_f32_16x16x32_bf16(Ah[1], Br[1],  aR,  0,0,0);
        aZ  = __builtin_amdgcn_mfma_f32_16x16x32_bf16(Ah[1], Bz[1],  aZ,  0,0,0);
        aNH = __builtin_amdgcn_mfma_f32_16x16x32_bf16(Ah[1], Bnh[1], aNH, 0,0,0);
        aR  = __builtin_amdgcn_mfma_f32_16x16x32_bf16(Ah[2], Br[2],  aR,  0,0,0);
        aZ  = __builtin_amdgcn_mfma_f32_16x16x32_bf16(Ah[2], Bz[2],  aZ,  0,0,0);
        aNX = __builtin_amdgcn_mfma_f32_16x16x32_bf16(Ah[2], Bnx,    aNX, 0,0,0);

        // finalize 2 valid rows per lane (D rows quad*4+r, col j)
        const int nb = cb ^ 1;
        #pragma unroll
        for (int r = 0; r < 2; ++r){
            float rg = __fdividef(1.0f, 1.0f + exp2f(-(aR[r] + bias_r)));
            float zg = __fdividef(1.0f, 1.0f + exp2f(-(aZ[r] + bias_z)));
            float yy = aNX[r] + bihn2 + rg * (aNH[r] + bhhn2);
            float ng = 1.0f - __fdividef(2.0f, exp2f(yy) + 1.0f);
            float hn = (1.0f - zg) * ng + zg * hreg[r];
            hreg[r] = hn;
            Abuf[nb][quad * 4 + r][j] = f2bf_rne(hn);
        }
        if (isx) Abuf[nb][xm][64 + xd] = f2bf_rne(xv);
        __syncthreads();
        cb = nb;
    }

    // ---- publish final h (fp32, from registers) ----
    #pragma unroll
    for (int r = 0; r < 2; ++r) hfp[2 * quad + r][j] = hreg[r];
    __syncthreads();

    // ================= heads: mu, logvar, z0 =================
    const int zrow = tid >> 4, zi = tid & 15;
    float z0v = 0.0f;
    if (tid < ROWS * LAT){
        float am = mub[zi], al = lvb[zi];
        const float4* pm = (const float4*)(muW + (size_t)zi * HID);
        const float4* pq = (const float4*)(lvW + (size_t)zi * HID);
        const float4* ph = (const float4*)(&hfp[zrow][0]);
        #pragma unroll
        for (int q = 0; q < 16; ++q){
            float4 wm = pm[q], wl = pq[q], hv = ph[q];
            am += wm.x*hv.x + wm.y*hv.y + wm.z*hv.z + wm.w*hv.w;
            al += wl.x*hv.x + wl.y*hv.y + wl.z*hv.z + wl.w*hv.w;
        }
        const size_t muBase = (size_t)B_TOTAL * T_LEN;
        out[muBase + (size_t)(b0 + zrow) * LAT + zi] = am;
        out[muBase + (size_t)B_TOTAL * LAT + (size_t)(b0 + zrow) * LAT + zi] = al;
        z0v = am + __expf(0.5f * al);
    }

    // ================= ODE: RK4, 24 fixed steps on [0,1] =================
    if (tid < ROWS * LAT){
        float ows[16];
        {
            const float4* pw = (const float4*)(oW + (size_t)zi * LAT);
            #pragma unroll
            for (int q = 0; q < 4; ++q){
                float4 w = pw[q];
                ows[4*q+0] = w.x; ows[4*q+1] = w.y; ows[4*q+2] = w.z; ows[4*q+3] = w.w;
            }
        }
        const float obv = ob[zi];
        float z = z0v;
        const float hstep = 1.0f / 24.0f;
        for (int s = 0; s < 24; ++s){
            float y, k1, k2, k3, k4;
            y = z;
            { float acc = obv;
              #pragma unroll
              for (int jj = 0; jj < 16; ++jj){ float yj = __shfl(y, jj, 16); acc = fmaf(ows[jj], yj, acc); }
              k1 = fmaxf(acc, 0.0f); }
            y = z + 0.5f * hstep * k1;
            { float acc = obv;
              #pragma unroll
              for (int jj = 0; jj < 16; ++jj){ float yj = __shfl(y, jj, 16); acc = fmaf(ows[jj], yj, acc); }
              k2 = fmaxf(acc, 0.0f); }
            y = z + 0.5f * hstep * k2;
            { float acc = obv;
              #pragma unroll
              for (int jj = 0; jj < 16; ++jj){ float yj = __shfl(y, jj, 16); acc = fmaf(ows[jj], yj, acc); }
              k3 = fmaxf(acc, 0.0f); }
            y = z + hstep * k3;
            { float acc = obv;
              #pragma unroll
              for (int jj = 0; jj < 16; ++jj){ float yj = __shfl(y, jj, 16); acc = fmaf(ows[jj], yj, acc); }
              k4 = fmaxf(acc, 0.0f); }
            z += (hstep / 6.0f) * (k1 + 2.0f*k2 + 2.0f*k3 + k4);
        }
        zsh[zrow][zi] = z;
    }
    __syncthreads();

    // ================= decoder fc: zd = relu(z @ dfW.T + dfb) =================
    for (int idx = tid; idx < ROWS * HID; idx += THREADS){
        const int row = idx >> 6, o = idx & 63;
        float acc = dfb[o];
        const float4* pw = (const float4*)(dfW + (size_t)o * LAT);
        const float4* pz = (const float4*)(&zsh[row][0]);
        #pragma unroll
        for (int q = 0; q < 4; ++q){
            float4 w = pw[q], zv = pz[q];
            acc += w.x*zv.x + w.y*zv.y + w.z*zv.z + w.w*zv.w;
        }
        zdsh[row][o] = fmaxf(acc, 0.0f);
    }
    __syncthreads();

    // xg_dec = zd @ dec_Wih.T + dec_bih
    if (tid < ROWS * 3){
        const int row = tid / 3, gg = tid % 3;
        float acc = dbih[gg];
        const float4* pw = (const float4*)(dWih + (size_t)gg * HID);
        const float4* pz = (const float4*)(&zdsh[row][0]);
        #pragma unroll
        for (int q = 0; q < 16; ++q){
            float4 w = pw[q], zv = pz[q];
            acc += w.x*zv.x + w.y*zv.y + w.z*zv.z + w.w*zv.w;
        }
        xgdsh[row][gg] = acc;
    }
    __syncthreads();

    // ================= decoder GRU (hidden dim 1), 512 steps =================
    if (tid < ROWS){
        const int row = tid;
        const float xr = xgdsh[row][0], xz = xgdsh[row][1], xn = xgdsh[row][2];
        const float A0 = dWhh[0], A1 = dWhh[1], A2 = dWhh[2];
        const float c0 = dbhh[0], c1 = dbhh[1], c2 = dbhh[2];
        float h = 0.0f;
        for (int t = 0; t < T_LEN; ++t){
            float rr = fast_sigmoid(xr + A0 * h + c0);
            float zz = fast_sigmoid(xz + A1 * h + c1);
            float nn = fast_tanh(xn + rr * (A2 * h + c2));
            h = (1.0f - zz) * nn + zz * h;
            outsh[row][t] = h;
        }
    }
    __syncthreads();

    // coalesced x_recon write: rows b0..b0+7 contiguous
    {
        const float4* ps = (const float4*)(&outsh[0][0]);
        float4* pd = (float4*)out;
        const size_t base4 = ((size_t)b0 * T_LEN) >> 2;
        for (int q = tid; q < (ROWS * T_LEN) / 4; q += THREADS)
            pd[base4 + q] = ps[q];
    }
}

extern "C" void kernel_launch(void* const* d_in, const int* in_sizes, int n_in,
                              void* d_out, int out_size, void* d_ws, size_t ws_size,
                              hipStream_t stream){
    glsde_kernel<<<B_TOTAL / ROWS, THREADS, 0, stream>>>(
        (const float*)d_in[0],  (const float*)d_in[1],  (const float*)d_in[2],
        (const float*)d_in[3],  (const float*)d_in[4],  (const float*)d_in[5],
        (const float*)d_in[6],  (const float*)d_in[7],  (const float*)d_in[8],
        (const float*)d_in[9],  (const float*)d_in[10], (const float*)d_in[11],
        (const float*)d_in[12], (const float*)d_in[13], (const float*)d_in[14],
        (const float*)d_in[15], (const float*)d_in[16], (float*)d_out);
}